// Round 2
// baseline (306.287 us; speedup 1.0000x reference)
//
#include <hip/hip_runtime.h>
#include <hip/hip_fp16.h>

// B=4, T=2048, C=1024. Single-head causal attention, fp32 in/out.
// Internals fp16 (MFMA f32_16x16x32_f16), fp32 accum + fp32 softmax.
// R2: swizzled LDS (conflict-free reads), operand-swapped MFMA for
// vectorized epilogues, fp16 scores in-place with P, PV longest-first.

typedef __attribute__((ext_vector_type(8))) _Float16 half8;
typedef __attribute__((ext_vector_type(4))) _Float16 half4;
typedef __attribute__((ext_vector_type(4))) float f32x4;

#define AS1 __attribute__((address_space(1)))
#define AS3 __attribute__((address_space(3)))

__device__ __forceinline__ void gload_lds16(const void* g, void* l) {
    // async global->LDS, 16B/lane; LDS dest = wave-uniform base + lane*16
    __builtin_amdgcn_global_load_lds((AS1 void*)g, (AS3 void*)l, 16, 0, 0);
}

// ---------------------------------------------------------------------------
// NT-GEMM core, 128x128 tile, 256 thr = 4 waves (64x64 quadrants), 4x4 MFMA
// 16x16x32 each. A[m][k] lda, B[n][k] ldb, k in [k0,k1) mult of 32.
// LDS swizzle: thread-chunk f holds global (row=f>>2, col=(f&3)^((f>>3)&3));
// fragment (R, colchunk=lq) lives at chunk 4R + ((lq ^ (R>>1)) & 3).
// -> 16 lanes/lq-group span all 8 bank-quads exactly 2x (2-way = free).
// SWAP: mfma(b, a) -> acc[mi][ni] holds C^T fragment (cols = 4 consecutive).
// ---------------------------------------------------------------------------
template<bool SWAP>
__device__ __forceinline__ void gemm_nt_core(
    const _Float16* __restrict__ A, const _Float16* __restrict__ B,
    int lda, int ldb, int k0, int k1,
    _Float16* ldsA, _Float16* ldsB, f32x4 acc[4][4])
{
    const int t    = threadIdx.x;
    const int lane = t & 63;
    const int wm   = (t >> 7) & 1;
    const int wn   = (t >> 6) & 1;
    const int lr   = lane & 15;
    const int lq   = lane >> 4;

    // staging: 512 x 16B chunks per tile, 2 per thread, swizzled global col
    const int f0 = t, f1 = t + 256;
    const int r0 = f0 >> 2, c0 = ((f0 & 3) ^ ((f0 >> 3) & 3)) * 8;
    const int r1 = f1 >> 2, c1 = ((f1 & 3) ^ ((f1 >> 3) & 3)) * 8;
    const _Float16* a0 = A + (size_t)r0 * lda + c0;
    const _Float16* a1 = A + (size_t)r1 * lda + c1;
    const _Float16* b0 = B + (size_t)r0 * ldb + c0;
    const _Float16* b1 = B + (size_t)r1 * ldb + c1;
    _Float16* lA0 = ldsA + f0 * 8;
    _Float16* lA1 = ldsA + f1 * 8;
    _Float16* lB0 = ldsB + f0 * 8;
    _Float16* lB1 = ldsB + f1 * 8;

    // fragment LDS offsets (halves), swizzled chunk per row
    int offA[4], offB[4];
#pragma unroll
    for (int i = 0; i < 4; ++i) {
        int Ra = wm * 64 + i * 16 + lr;
        int Rb = wn * 64 + i * 16 + lr;
        offA[i] = (Ra * 4 + ((lq ^ (Ra >> 1)) & 3)) * 8;
        offB[i] = (Rb * 4 + ((lq ^ (Rb >> 1)) & 3)) * 8;
    }

    for (int k = k0; k < k1; k += 32) {
        __syncthreads();               // prev compute done before overwrite
        gload_lds16(a0 + k, lA0);
        gload_lds16(a1 + k, lA1);
        gload_lds16(b0 + k, lB0);
        gload_lds16(b1 + k, lB1);
        __syncthreads();               // staging visible

        half8 af[4], bf[4];
#pragma unroll
        for (int i = 0; i < 4; ++i) {
            af[i] = *(const half8*)(ldsA + offA[i]);
            bf[i] = *(const half8*)(ldsB + offB[i]);
        }
#pragma unroll
        for (int mi = 0; mi < 4; ++mi)
#pragma unroll
            for (int ni = 0; ni < 4; ++ni) {
                if constexpr (SWAP)
                    acc[mi][ni] = __builtin_amdgcn_mfma_f32_16x16x32_f16(
                        bf[ni], af[mi], acc[mi][ni], 0, 0, 0);
                else
                    acc[mi][ni] = __builtin_amdgcn_mfma_f32_16x16x32_f16(
                        af[mi], bf[ni], acc[mi][ni], 0, 0, 0);
            }
    }
}

// ---------------------------------------------------------------------------
__global__ __launch_bounds__(256) void f32tof16_k(
    const float* __restrict__ in, _Float16* __restrict__ out, int n)
{
    int i = (blockIdx.x * 256 + threadIdx.x) * 4;
    if (i < n) {
        float4 f = *(const float4*)(in + i);
        half4 h = { (_Float16)f.x, (_Float16)f.y, (_Float16)f.z, (_Float16)f.w };
        *(half4*)(out + i) = h;
    }
}

// ---------------------------------------------------------------------------
// QKV: out = x @ W^T. Z=0 -> Q[t][d], Z=1 -> K[s][d] (swapped MFMA, half4
// along d). Z=2 -> Vt[d][t] (unswapped, half4 along t).
// ---------------------------------------------------------------------------
template<int Z>
__global__ __launch_bounds__(256) void qkv_gemm_k(
    const _Float16* __restrict__ xh, const _Float16* __restrict__ W,
    _Float16* __restrict__ O)
{
    __shared__ __align__(16) _Float16 ldsA[128 * 32];
    __shared__ __align__(16) _Float16 ldsB[128 * 32];
    const int tileM = blockIdx.x * 128;
    const int tileN = blockIdx.y * 128;

    f32x4 acc[4][4] = {};
    gemm_nt_core<(Z != 2)>(xh + (size_t)tileM * 1024, W + (size_t)tileN * 1024,
                           1024, 1024, 0, 1024, ldsA, ldsB, acc);

    const int lane = threadIdx.x & 63;
    const int wm = (threadIdx.x >> 7) & 1, wn = (threadIdx.x >> 6) & 1;
    const int lr = lane & 15, lq = lane >> 4;

    if constexpr (Z == 2) {
        // unswapped: rows (t) consecutive per lane -> half4 into Vt[b][d][t]
#pragma unroll
        for (int mi = 0; mi < 4; ++mi)
#pragma unroll
            for (int ni = 0; ni < 4; ++ni) {
                int m0 = tileM + wm * 64 + mi * 16 + lq * 4;   // 4 consecutive t
                int n  = tileN + wn * 64 + ni * 16 + lr;       // d
                int b = m0 >> 11, tt = m0 & 2047;
                half4 h = { (_Float16)acc[mi][ni][0], (_Float16)acc[mi][ni][1],
                            (_Float16)acc[mi][ni][2], (_Float16)acc[mi][ni][3] };
                *(half4*)(O + (size_t)b * 2048 * 1024 + (size_t)n * 2048 + tt) = h;
            }
    } else {
        // swapped: cols (d) consecutive per lane -> half4 into O[t][d]
#pragma unroll
        for (int mi = 0; mi < 4; ++mi)
#pragma unroll
            for (int ni = 0; ni < 4; ++ni) {
                int tt = tileM + wm * 64 + mi * 16 + lr;
                int d0 = tileN + wn * 64 + ni * 16 + lq * 4;
                half4 h = { (_Float16)acc[mi][ni][0], (_Float16)acc[mi][ni][1],
                            (_Float16)acc[mi][ni][2], (_Float16)acc[mi][ni][3] };
                *(half4*)(O + (size_t)tt * 1024 + d0) = h;
            }
    }
}

// ---------------------------------------------------------------------------
// Scores (fp16): S[b][t][s] = scale*(Q[t].K[s]) for s<=t, 0 for s>t within
// the tile. Swapped MFMA -> half4 along s. Skips fully-masked tiles.
// ---------------------------------------------------------------------------
__global__ __launch_bounds__(256) void scores_gemm_k(
    const _Float16* __restrict__ Q, const _Float16* __restrict__ K,
    _Float16* __restrict__ S)
{
    const int tileT = blockIdx.x * 128;
    const int tileS = blockIdx.y * 128;
    if (tileS > tileT + 127) return;   // fully above diagonal
    const int b = blockIdx.z;

    __shared__ __align__(16) _Float16 ldsA[128 * 32];
    __shared__ __align__(16) _Float16 ldsB[128 * 32];
    f32x4 acc[4][4] = {};
    gemm_nt_core<true>(Q + (size_t)b * 2048 * 1024 + (size_t)tileT * 1024,
                       K + (size_t)b * 2048 * 1024 + (size_t)tileS * 1024,
                       1024, 1024, 0, 1024, ldsA, ldsB, acc);

    const int lane = threadIdx.x & 63;
    const int wm = (threadIdx.x >> 7) & 1, wn = (threadIdx.x >> 6) & 1;
    const int lr = lane & 15, lq = lane >> 4;
    const float scale = 0.03125f;  // 1024^-0.5

#pragma unroll
    for (int mi = 0; mi < 4; ++mi)
#pragma unroll
        for (int ni = 0; ni < 4; ++ni) {
            int tt = tileT + wm * 64 + mi * 16 + lr;
            int s0 = tileS + wn * 64 + ni * 16 + lq * 4;
            half4 h;
#pragma unroll
            for (int r = 0; r < 4; ++r)
                h[r] = (s0 + r <= tt) ? (_Float16)(acc[mi][ni][r] * scale)
                                      : (_Float16)0.f;
            *(half4*)(S + ((size_t)b * 2048 + tt) * 2048 + s0) = h;
        }
}

// ---------------------------------------------------------------------------
// Softmax over row [0..t], fp16 in -> fp16 P in place (same buffer/stride).
// Entries s>t inside the diagonal tile already hold 0 from scores; beyond
// tileT+128 PV never reads. No zero-fill needed.
// ---------------------------------------------------------------------------
__global__ __launch_bounds__(256) void softmax_k(_Float16* __restrict__ S)
{
    const int t = blockIdx.x, b = blockIdx.y;
    _Float16* row = S + ((size_t)b * 2048 + t) * 2048;
    const int len = t + 1;
    const int tid = threadIdx.x;

    float v[8];
    int cnt = 0;
    float mx = -1e30f;
    for (int s = tid; s < len; s += 256) {
        float x = (float)row[s];
        v[cnt++] = x;
        mx = fmaxf(mx, x);
    }
    __shared__ float wred[4];
#pragma unroll
    for (int o = 32; o > 0; o >>= 1) mx = fmaxf(mx, __shfl_xor(mx, o));
    if ((tid & 63) == 0) wred[tid >> 6] = mx;
    __syncthreads();
    mx = fmaxf(fmaxf(wred[0], wred[1]), fmaxf(wred[2], wred[3]));

    float sum = 0.f;
    for (int i = 0; i < cnt; ++i) {
        float e = __expf(v[i] - mx);
        v[i] = e;
        sum += e;
    }
#pragma unroll
    for (int o = 32; o > 0; o >>= 1) sum += __shfl_xor(sum, o);
    __shared__ float wsum[4];
    if ((tid & 63) == 0) wsum[tid >> 6] = sum;
    __syncthreads();
    sum = wsum[0] + wsum[1] + wsum[2] + wsum[3];
    const float inv = 1.0f / sum;

    cnt = 0;
    for (int s = tid; s < len; s += 256) row[s] = (_Float16)(v[cnt++] * inv);
}

// ---------------------------------------------------------------------------
// PV: out[b][t][d] = sum_s P[t][s] Vt[d][s]. Swapped MFMA -> float4 along d.
// K-loop capped at tileT+128 (causal). Longest tiles launched first.
// ---------------------------------------------------------------------------
__global__ __launch_bounds__(256) void pv_gemm_k(
    const _Float16* __restrict__ P, const _Float16* __restrict__ Vt,
    float* __restrict__ out)
{
    __shared__ __align__(16) _Float16 ldsA[128 * 32];
    __shared__ __align__(16) _Float16 ldsB[128 * 32];
    const int tileT = (15 - blockIdx.x) * 128;    // longest-first
    const int tileD = blockIdx.y * 128;
    const int b     = blockIdx.z;
    const int kEnd  = tileT + 128;

    f32x4 acc[4][4] = {};
    gemm_nt_core<true>(P + ((size_t)b * 2048 + tileT) * 2048,
                       Vt + (size_t)b * 1024 * 2048 + (size_t)tileD * 2048,
                       2048, 2048, 0, kEnd, ldsA, ldsB, acc);

    const int lane = threadIdx.x & 63;
    const int wm = (threadIdx.x >> 7) & 1, wn = (threadIdx.x >> 6) & 1;
    const int lr = lane & 15, lq = lane >> 4;

#pragma unroll
    for (int mi = 0; mi < 4; ++mi)
#pragma unroll
        for (int ni = 0; ni < 4; ++ni) {
            int tt = tileT + wm * 64 + mi * 16 + lr;
            int d0 = tileD + wn * 64 + ni * 16 + lq * 4;
            *(f32x4*)(out + ((size_t)b * 2048 + tt) * 1024 + d0) = acc[mi][ni];
        }
}

// ---------------------------------------------------------------------------
extern "C" void kernel_launch(void* const* d_in, const int* in_sizes, int n_in,
                              void* d_out, int out_size, void* d_ws, size_t ws_size,
                              hipStream_t stream)
{
    const float* x  = (const float*)d_in[0];
    const float* Wq = (const float*)d_in[1];
    const float* Wk = (const float*)d_in[2];
    const float* Wv = (const float*)d_in[3];
    float* out = (float*)d_out;

    char* ws = (char*)d_ws;
    // layout (MB): xh 0..16 | Wh 16..22 | Q 22..38 | K 38..54 | Vt 54..70 |
    // S16 70..102 (P aliases S).  Total 102 MB.
    _Float16* xh = (_Float16*)(ws);
    _Float16* Wh = (_Float16*)(ws + (16u << 20));
    _Float16* Qh = (_Float16*)(ws + (22u << 20));
    _Float16* Kh = (_Float16*)(ws + (38u << 20));
    _Float16* Vt = (_Float16*)(ws + (54u << 20));
    _Float16* S  = (_Float16*)(ws + (70u << 20));

    f32tof16_k<<<8192, 256, 0, stream>>>(x, xh, 4 * 2048 * 1024);
    f32tof16_k<<<1024, 256, 0, stream>>>(Wq, Wh,                1024 * 1024);
    f32tof16_k<<<1024, 256, 0, stream>>>(Wk, Wh + 1024 * 1024,  1024 * 1024);
    f32tof16_k<<<1024, 256, 0, stream>>>(Wv, Wh + 2048 * 1024,  1024 * 1024);

    qkv_gemm_k<0><<<dim3(64, 8), 256, 0, stream>>>(xh, Wh,                Qh);
    qkv_gemm_k<1><<<dim3(64, 8), 256, 0, stream>>>(xh, Wh + 1024 * 1024,  Kh);
    qkv_gemm_k<2><<<dim3(64, 8), 256, 0, stream>>>(xh, Wh + 2048 * 1024,  Vt);

    scores_gemm_k<<<dim3(16, 16, 4), 256, 0, stream>>>(Qh, Kh, S);
    softmax_k<<<dim3(2048, 4), 256, 0, stream>>>(S);
    pv_gemm_k<<<dim3(16, 8, 4), 256, 0, stream>>>(S, Vt, out);
}

// Round 3
// 300.677 us; speedup vs baseline: 1.0187x; 1.0187x over previous
//
#include <hip/hip_runtime.h>
#include <hip/hip_fp16.h>

// B=4, T=2048, C=1024. Single-head causal attention, fp32 in/out.
// Internals fp16 (MFMA f32_16x16x32_f16), fp32 accum + fp32 softmax.
// R3: re-fused QKV (1536-block launch, 6 blocks/CU), templated GEMM core
// with 64x128 tiles for scores/PV (2x block count, finer causal K-grain),
// swizzled conflict-free LDS, vectorized epilogues, fp16 S/P in place.

typedef __attribute__((ext_vector_type(8))) _Float16 half8;
typedef __attribute__((ext_vector_type(4))) _Float16 half4;
typedef __attribute__((ext_vector_type(4))) float f32x4;

#define AS1 __attribute__((address_space(1)))
#define AS3 __attribute__((address_space(3)))

__device__ __forceinline__ void gload_lds16(const void* g, void* l) {
    // async global->LDS, 16B/lane; LDS dest = wave-uniform base + lane*16
    __builtin_amdgcn_global_load_lds((AS1 void*)g, (AS3 void*)l, 16, 0, 0);
}

// ---------------------------------------------------------------------------
// NT-GEMM core, TM x TN tile, 256 thr = 4 waves. Each wave covers
// (TM/2)x(TN/2), i.e. (TM/32)x(TN/32) fragments of 16x16x32 MFMA.
// A[m][k] lda, B[n][k] ldb, k in [k0,k1) multiples of 32.
// LDS swizzle: chunk f holds global (row=f>>2, colchunk=(f&3)^((f>>3)&3));
// fragment (row R, colchunk lq) at chunk 4R + ((lq^(R>>1))&3). Over 16 lanes
// the chunks cover all 8 bank-quads exactly twice -> 2-way = free (verified
// R2: SQ_LDS_BANK_CONFLICT = 0).
// SWAP: mfma(b,a) -> C^T fragments (cols consecutive per lane).
// ---------------------------------------------------------------------------
template<int TM, int TN, bool SWAP>
__device__ __forceinline__ void gemm_nt_core(
    const _Float16* __restrict__ A, const _Float16* __restrict__ B,
    int lda, int ldb, int k0, int k1,
    _Float16* ldsA, _Float16* ldsB, f32x4 acc[TM / 32][TN / 32])
{
    constexpr int FM = TM / 32, FN = TN / 32;
    constexpr int NA = TM / 64, NB = TN / 64;   // 16B chunks per thread
    const int t    = threadIdx.x;
    const int lane = t & 63;
    const int wm   = (t >> 7) & 1;
    const int wn   = (t >> 6) & 1;
    const int lr   = lane & 15;
    const int lq   = lane >> 4;

    const _Float16* ga[NA]; _Float16* la[NA];
    const _Float16* gb[NB]; _Float16* lb[NB];
#pragma unroll
    for (int i = 0; i < NA; ++i) {
        int f = t + 256 * i;
        int r = f >> 2, c = ((f & 3) ^ ((f >> 3) & 3)) * 8;
        ga[i] = A + (size_t)r * lda + c;
        la[i] = ldsA + f * 8;
    }
#pragma unroll
    for (int i = 0; i < NB; ++i) {
        int f = t + 256 * i;
        int r = f >> 2, c = ((f & 3) ^ ((f >> 3) & 3)) * 8;
        gb[i] = B + (size_t)r * ldb + c;
        lb[i] = ldsB + f * 8;
    }

    int offA[FM], offB[FN];
#pragma unroll
    for (int i = 0; i < FM; ++i) {
        int R = wm * (TM / 2) + i * 16 + lr;
        offA[i] = (R * 4 + ((lq ^ (R >> 1)) & 3)) * 8;
    }
#pragma unroll
    for (int i = 0; i < FN; ++i) {
        int R = wn * (TN / 2) + i * 16 + lr;
        offB[i] = (R * 4 + ((lq ^ (R >> 1)) & 3)) * 8;
    }

    for (int k = k0; k < k1; k += 32) {
        __syncthreads();               // prev compute done before overwrite
#pragma unroll
        for (int i = 0; i < NA; ++i) gload_lds16(ga[i] + k, la[i]);
#pragma unroll
        for (int i = 0; i < NB; ++i) gload_lds16(gb[i] + k, lb[i]);
        __syncthreads();               // staging visible

        half8 af[FM], bf[FN];
#pragma unroll
        for (int i = 0; i < FM; ++i) af[i] = *(const half8*)(ldsA + offA[i]);
#pragma unroll
        for (int i = 0; i < FN; ++i) bf[i] = *(const half8*)(ldsB + offB[i]);
#pragma unroll
        for (int mi = 0; mi < FM; ++mi)
#pragma unroll
            for (int ni = 0; ni < FN; ++ni) {
                if constexpr (SWAP)
                    acc[mi][ni] = __builtin_amdgcn_mfma_f32_16x16x32_f16(
                        bf[ni], af[mi], acc[mi][ni], 0, 0, 0);
                else
                    acc[mi][ni] = __builtin_amdgcn_mfma_f32_16x16x32_f16(
                        af[mi], bf[ni], acc[mi][ni], 0, 0, 0);
            }
    }
}

// ---------------------------------------------------------------------------
__global__ __launch_bounds__(256) void f32tof16_k(
    const float* __restrict__ in, _Float16* __restrict__ out, int n)
{
    int i = (blockIdx.x * 256 + threadIdx.x) * 4;
    if (i < n) {
        float4 f = *(const float4*)(in + i);
        half4 h = { (_Float16)f.x, (_Float16)f.y, (_Float16)f.z, (_Float16)f.w };
        *(half4*)(out + i) = h;
    }
}

// W converts fused: blockIdx.y selects source; out = concat(Wq,Wk,Wv) fp16.
__global__ __launch_bounds__(256) void wconv_k(
    const float* __restrict__ Wq, const float* __restrict__ Wk,
    const float* __restrict__ Wv, _Float16* __restrict__ out)
{
    const float* src = (blockIdx.y == 0) ? Wq : (blockIdx.y == 1) ? Wk : Wv;
    int i = (blockIdx.x * 256 + threadIdx.x) * 4;
    float4 f = *(const float4*)(src + i);
    half4 h = { (_Float16)f.x, (_Float16)f.y, (_Float16)f.z, (_Float16)f.w };
    *(half4*)(out + (size_t)blockIdx.y * 1024 * 1024 + i) = h;
}

// ---------------------------------------------------------------------------
// Fused QKV: one launch, grid (64,8,3) = 1536 blocks (6/CU co-resident).
// z=0 -> Q[t][d], z=1 -> K[s][d] (swapped, half4 along d);
// z=2 -> Vt[b][d][t] (unswapped, half4 along t).
// ---------------------------------------------------------------------------
__global__ __launch_bounds__(256) void qkv_gemm_k(
    const _Float16* __restrict__ xh, const _Float16* __restrict__ Wh,
    _Float16* __restrict__ Q, _Float16* __restrict__ K, _Float16* __restrict__ Vt)
{
    __shared__ __align__(16) _Float16 ldsA[128 * 32];
    __shared__ __align__(16) _Float16 ldsB[128 * 32];
    const int tileM = blockIdx.x * 128;
    const int tileN = blockIdx.y * 128;
    const int z     = blockIdx.z;
    const _Float16* W = Wh + (size_t)z * 1024 * 1024;

    const int lane = threadIdx.x & 63;
    const int wm = (threadIdx.x >> 7) & 1, wn = (threadIdx.x >> 6) & 1;
    const int lr = lane & 15, lq = lane >> 4;

    if (z == 2) {
        f32x4 acc[4][4] = {};
        gemm_nt_core<128, 128, false>(xh + (size_t)tileM * 1024,
                                      W + (size_t)tileN * 1024,
                                      1024, 1024, 0, 1024, ldsA, ldsB, acc);
        // unswapped: 4 consecutive t per lane -> half4 into Vt[b][d][t]
#pragma unroll
        for (int mi = 0; mi < 4; ++mi)
#pragma unroll
            for (int ni = 0; ni < 4; ++ni) {
                int m0 = tileM + wm * 64 + mi * 16 + lq * 4;
                int n  = tileN + wn * 64 + ni * 16 + lr;
                int b = m0 >> 11, tt = m0 & 2047;
                half4 h = { (_Float16)acc[mi][ni][0], (_Float16)acc[mi][ni][1],
                            (_Float16)acc[mi][ni][2], (_Float16)acc[mi][ni][3] };
                *(half4*)(Vt + (size_t)b * 2048 * 1024 + (size_t)n * 2048 + tt) = h;
            }
    } else {
        f32x4 acc[4][4] = {};
        gemm_nt_core<128, 128, true>(xh + (size_t)tileM * 1024,
                                     W + (size_t)tileN * 1024,
                                     1024, 1024, 0, 1024, ldsA, ldsB, acc);
        _Float16* O = (z == 0) ? Q : K;
        // swapped: 4 consecutive d per lane -> half4 into O[t][d]
#pragma unroll
        for (int mi = 0; mi < 4; ++mi)
#pragma unroll
            for (int ni = 0; ni < 4; ++ni) {
                int tt = tileM + wm * 64 + mi * 16 + lr;
                int d0 = tileN + wn * 64 + ni * 16 + lq * 4;
                half4 h = { (_Float16)acc[mi][ni][0], (_Float16)acc[mi][ni][1],
                            (_Float16)acc[mi][ni][2], (_Float16)acc[mi][ni][3] };
                *(half4*)(O + (size_t)tt * 1024 + d0) = h;
            }
    }
}

// ---------------------------------------------------------------------------
// Scores (fp16): 64(T) x 128(S) tiles -> 1088 active blocks. Swapped MFMA,
// half4 along s, causal mask to 0 in-tile. Skips fully-masked tiles.
// ---------------------------------------------------------------------------
__global__ __launch_bounds__(256) void scores_gemm_k(
    const _Float16* __restrict__ Q, const _Float16* __restrict__ K,
    _Float16* __restrict__ S)
{
    const int ti = blockIdx.x;           // 0..31 (64-row T tiles)
    const int si = blockIdx.y;           // 0..15 (128-col S tiles)
    if (si > (ti >> 1)) return;          // fully above diagonal
    const int tileT = ti * 64, tileS = si * 128, b = blockIdx.z;

    __shared__ __align__(16) _Float16 ldsA[64 * 32];
    __shared__ __align__(16) _Float16 ldsB[128 * 32];
    f32x4 acc[2][4] = {};
    gemm_nt_core<64, 128, true>(Q + (size_t)b * 2048 * 1024 + (size_t)tileT * 1024,
                                K + (size_t)b * 2048 * 1024 + (size_t)tileS * 1024,
                                1024, 1024, 0, 1024, ldsA, ldsB, acc);

    const int lane = threadIdx.x & 63;
    const int wm = (threadIdx.x >> 7) & 1, wn = (threadIdx.x >> 6) & 1;
    const int lr = lane & 15, lq = lane >> 4;
    const float scale = 0.03125f;  // 1024^-0.5

#pragma unroll
    for (int mi = 0; mi < 2; ++mi)
#pragma unroll
        for (int ni = 0; ni < 4; ++ni) {
            int tt = tileT + wm * 32 + mi * 16 + lr;
            int s0 = tileS + wn * 64 + ni * 16 + lq * 4;
            half4 h;
#pragma unroll
            for (int r = 0; r < 4; ++r)
                h[r] = (s0 + r <= tt) ? (_Float16)(acc[mi][ni][r] * scale)
                                      : (_Float16)0.f;
            *(half4*)(S + ((size_t)b * 2048 + tt) * 2048 + s0) = h;
        }
}

// ---------------------------------------------------------------------------
// Softmax over row [0..t], fp16 in -> fp16 P in place. In-tile s>t already 0
// from scores; PV never reads past its kEnd. No zero-fill needed.
// ---------------------------------------------------------------------------
__global__ __launch_bounds__(256) void softmax_k(_Float16* __restrict__ S)
{
    const int t = blockIdx.x, b = blockIdx.y;
    _Float16* row = S + ((size_t)b * 2048 + t) * 2048;
    const int len = t + 1;
    const int tid = threadIdx.x;

    float v[8];
    int cnt = 0;
    float mx = -1e30f;
    for (int s = tid; s < len; s += 256) {
        float x = (float)row[s];
        v[cnt++] = x;
        mx = fmaxf(mx, x);
    }
    __shared__ float wred[4];
#pragma unroll
    for (int o = 32; o > 0; o >>= 1) mx = fmaxf(mx, __shfl_xor(mx, o));
    if ((tid & 63) == 0) wred[tid >> 6] = mx;
    __syncthreads();
    mx = fmaxf(fmaxf(wred[0], wred[1]), fmaxf(wred[2], wred[3]));

    float sum = 0.f;
    for (int i = 0; i < cnt; ++i) {
        float e = __expf(v[i] - mx);
        v[i] = e;
        sum += e;
    }
#pragma unroll
    for (int o = 32; o > 0; o >>= 1) sum += __shfl_xor(sum, o);
    __shared__ float wsum[4];
    if ((tid & 63) == 0) wsum[tid >> 6] = sum;
    __syncthreads();
    sum = wsum[0] + wsum[1] + wsum[2] + wsum[3];
    const float inv = 1.0f / sum;

    cnt = 0;
    for (int s = tid; s < len; s += 256) row[s] = (_Float16)(v[cnt++] * inv);
}

// ---------------------------------------------------------------------------
// PV: 64(T) x 128(D) tiles -> 1024 blocks, kEnd = tileT+64 (finer causal
// grain). Swapped MFMA -> float4 along d.
// ---------------------------------------------------------------------------
__global__ __launch_bounds__(256) void pv_gemm_k(
    const _Float16* __restrict__ P, const _Float16* __restrict__ Vt,
    float* __restrict__ out)
{
    __shared__ __align__(16) _Float16 ldsA[64 * 32];
    __shared__ __align__(16) _Float16 ldsB[128 * 32];
    const int tileT = (31 - blockIdx.x) * 64;   // longest-first
    const int tileD = blockIdx.y * 128;
    const int b     = blockIdx.z;
    const int kEnd  = tileT + 64;

    f32x4 acc[2][4] = {};
    gemm_nt_core<64, 128, true>(P + ((size_t)b * 2048 + tileT) * 2048,
                                Vt + (size_t)b * 1024 * 2048 + (size_t)tileD * 2048,
                                2048, 2048, 0, kEnd, ldsA, ldsB, acc);

    const int lane = threadIdx.x & 63;
    const int wm = (threadIdx.x >> 7) & 1, wn = (threadIdx.x >> 6) & 1;
    const int lr = lane & 15, lq = lane >> 4;

#pragma unroll
    for (int mi = 0; mi < 2; ++mi)
#pragma unroll
        for (int ni = 0; ni < 4; ++ni) {
            int tt = tileT + wm * 32 + mi * 16 + lr;
            int d0 = tileD + wn * 64 + ni * 16 + lq * 4;
            *(f32x4*)(out + ((size_t)b * 2048 + tt) * 1024 + d0) = acc[mi][ni];
        }
}

// ---------------------------------------------------------------------------
extern "C" void kernel_launch(void* const* d_in, const int* in_sizes, int n_in,
                              void* d_out, int out_size, void* d_ws, size_t ws_size,
                              hipStream_t stream)
{
    const float* x  = (const float*)d_in[0];
    const float* Wq = (const float*)d_in[1];
    const float* Wk = (const float*)d_in[2];
    const float* Wv = (const float*)d_in[3];
    float* out = (float*)d_out;

    char* ws = (char*)d_ws;
    // layout (MB): xh 0..16 | Wh 16..22 | Q 22..38 | K 38..54 | Vt 54..70 |
    // S16 70..102 (P aliases S).  Total 102 MB.
    _Float16* xh = (_Float16*)(ws);
    _Float16* Wh = (_Float16*)(ws + (16u << 20));
    _Float16* Qh = (_Float16*)(ws + (22u << 20));
    _Float16* Kh = (_Float16*)(ws + (38u << 20));
    _Float16* Vt = (_Float16*)(ws + (54u << 20));
    _Float16* S  = (_Float16*)(ws + (70u << 20));

    f32tof16_k<<<8192, 256, 0, stream>>>(x, xh, 4 * 2048 * 1024);
    wconv_k<<<dim3(1024, 3), 256, 0, stream>>>(Wq, Wk, Wv, Wh);

    qkv_gemm_k<<<dim3(64, 8, 3), 256, 0, stream>>>(xh, Wh, Qh, Kh, Vt);

    scores_gemm_k<<<dim3(32, 16, 4), 256, 0, stream>>>(Qh, Kh, S);
    softmax_k<<<dim3(2048, 4), 256, 0, stream>>>(S);
    pv_gemm_k<<<dim3(32, 8, 4), 256, 0, stream>>>(S, Vt, out);
}

// Round 4
// 284.844 us; speedup vs baseline: 1.0753x; 1.0556x over previous
//
#include <hip/hip_runtime.h>
#include <hip/hip_fp16.h>

// B=4, T=2048, C=1024. Single-head causal attention, fp32 in/out.
// Internals fp16 (MFMA f32_16x16x32_f16), fp32 accum + fp32 softmax.
// R4: (1) double-buffered K-loop with raw s_barrier + s_waitcnt vmcnt(N)
// (prefetch never drained by a vmcnt(0) barrier), (2) wave-per-row half8
// softmax (no block barriers), (3) scores 128x128, pv 128x64 (1024 blocks).

typedef __attribute__((ext_vector_type(8))) _Float16 half8;
typedef __attribute__((ext_vector_type(4))) _Float16 half4;
typedef __attribute__((ext_vector_type(4))) float f32x4;

#define AS1 __attribute__((address_space(1)))
#define AS3 __attribute__((address_space(3)))

__device__ __forceinline__ void gload_lds16(const void* g, void* l) {
    // async global->LDS, 16B/lane; LDS dest = wave-uniform base + lane*16
    __builtin_amdgcn_global_load_lds((AS1 void*)g, (AS3 void*)l, 16, 0, 0);
}

// s_barrier WITHOUT the compiler's implicit s_waitcnt vmcnt(0) drain.
// asm memory clobbers pin LDS/global ops on their side of the barrier.
__device__ __forceinline__ void barrier_np() {
    __asm__ volatile("" ::: "memory");
    __builtin_amdgcn_s_barrier();
    __asm__ volatile("" ::: "memory");
}

// ---------------------------------------------------------------------------
// Double-buffered NT-GEMM core, TM x TN tile, 256 thr = 4 waves, each wave
// (TM/2)x(TN/2) of 16x16x32 MFMA fragments. A[m][k] lda, B[n][k] ldb.
// LDS swizzle (verified conflict-free, R2: SQ_LDS_BANK_CONFLICT=0):
// chunk f holds global (row=f>>2, colchunk=(f&3)^((f>>3)&3)); fragment
// (row R, colchunk lq) at chunk 4R + ((lq^(R>>1))&3).
// Pipeline per iter k:
//   issue loads(k+32)->buf^1     (safe: buf^1 readers done at barrier E of k-32)
//   s_waitcnt vmcnt(NA+NB)       (my loads(k)->buf landed; k+32 still in flight)
//   s_barrier                    (C: everyone's loads(k) landed)
//   compute tile k from buf      (ds_reads complete before their MFMA uses)
//   s_barrier                    (E: everyone done reading buf)
// No vmcnt(0) anywhere in the loop: prefetch latency hidden under compute.
// ---------------------------------------------------------------------------
template<int TM, int TN, bool SWAP>
__device__ __forceinline__ void gemm_nt_dbuf(
    const _Float16* __restrict__ A, const _Float16* __restrict__ B,
    int lda, int ldb, int k0, int k1,
    _Float16* ldsA, _Float16* ldsB,      // sized 2*TM*32 and 2*TN*32
    f32x4 acc[TM / 32][TN / 32])
{
    constexpr int FM = TM / 32, FN = TN / 32;
    constexpr int NA = TM / 64, NB = TN / 64;        // 16B chunks per thread
    constexpr int WAIT_IMM = 0xF70 | (NA + NB);      // vmcnt(NA+NB), exp/lgkm free
    const int t    = threadIdx.x;
    const int lane = t & 63;
    const int wm   = (t >> 7) & 1;
    const int wn   = (t >> 6) & 1;
    const int lr   = lane & 15;
    const int lq   = lane >> 4;

    const _Float16* ga[NA]; int loA[NA];
    const _Float16* gb[NB]; int loB[NB];
#pragma unroll
    for (int i = 0; i < NA; ++i) {
        int f = t + 256 * i;
        int r = f >> 2, c = ((f & 3) ^ ((f >> 3) & 3)) * 8;
        ga[i] = A + (size_t)r * lda + c;
        loA[i] = f * 8;
    }
#pragma unroll
    for (int i = 0; i < NB; ++i) {
        int f = t + 256 * i;
        int r = f >> 2, c = ((f & 3) ^ ((f >> 3) & 3)) * 8;
        gb[i] = B + (size_t)r * ldb + c;
        loB[i] = f * 8;
    }

    int offA[FM], offB[FN];
#pragma unroll
    for (int i = 0; i < FM; ++i) {
        int R = wm * (TM / 2) + i * 16 + lr;
        offA[i] = (R * 4 + ((lq ^ (R >> 1)) & 3)) * 8;
    }
#pragma unroll
    for (int i = 0; i < FN; ++i) {
        int R = wn * (TN / 2) + i * 16 + lr;
        offB[i] = (R * 4 + ((lq ^ (R >> 1)) & 3)) * 8;
    }

    // prologue: stage tile k0 into buffer 0
#pragma unroll
    for (int i = 0; i < NA; ++i) gload_lds16(ga[i] + k0, ldsA + loA[i]);
#pragma unroll
    for (int i = 0; i < NB; ++i) gload_lds16(gb[i] + k0, ldsB + loB[i]);

    int sel = 0;
    for (int k = k0; k < k1; k += 32) {
        const int kp = (k + 32 < k1) ? k + 32 : k;   // clamp: last iter re-loads (unused)
        _Float16* pA = ldsA + (sel ^ 1) * (TM * 32);
        _Float16* pB = ldsB + (sel ^ 1) * (TN * 32);
#pragma unroll
        for (int i = 0; i < NA; ++i) gload_lds16(ga[i] + kp, pA + loA[i]);
#pragma unroll
        for (int i = 0; i < NB; ++i) gload_lds16(gb[i] + kp, pB + loB[i]);

        __builtin_amdgcn_s_waitcnt(WAIT_IMM);        // my tile-k loads landed
        barrier_np();                                // everyone's landed

        const _Float16* bufA = ldsA + sel * (TM * 32);
        const _Float16* bufB = ldsB + sel * (TN * 32);
        half8 af[FM], bf[FN];
#pragma unroll
        for (int i = 0; i < FM; ++i) af[i] = *(const half8*)(bufA + offA[i]);
#pragma unroll
        for (int i = 0; i < FN; ++i) bf[i] = *(const half8*)(bufB + offB[i]);
#pragma unroll
        for (int mi = 0; mi < FM; ++mi)
#pragma unroll
            for (int ni = 0; ni < FN; ++ni) {
                if constexpr (SWAP)
                    acc[mi][ni] = __builtin_amdgcn_mfma_f32_16x16x32_f16(
                        bf[ni], af[mi], acc[mi][ni], 0, 0, 0);
                else
                    acc[mi][ni] = __builtin_amdgcn_mfma_f32_16x16x32_f16(
                        af[mi], bf[ni], acc[mi][ni], 0, 0, 0);
            }
        barrier_np();                                // all reads of buf done
        sel ^= 1;
    }
}

// ---------------------------------------------------------------------------
__global__ __launch_bounds__(256) void f32tof16_k(
    const float* __restrict__ in, _Float16* __restrict__ out, int n)
{
    int i = (blockIdx.x * 256 + threadIdx.x) * 4;
    if (i < n) {
        float4 f = *(const float4*)(in + i);
        half4 h = { (_Float16)f.x, (_Float16)f.y, (_Float16)f.z, (_Float16)f.w };
        *(half4*)(out + i) = h;
    }
}

__global__ __launch_bounds__(256) void wconv_k(
    const float* __restrict__ Wq, const float* __restrict__ Wk,
    const float* __restrict__ Wv, _Float16* __restrict__ out)
{
    const float* src = (blockIdx.y == 0) ? Wq : (blockIdx.y == 1) ? Wk : Wv;
    int i = (blockIdx.x * 256 + threadIdx.x) * 4;
    float4 f = *(const float4*)(src + i);
    half4 h = { (_Float16)f.x, (_Float16)f.y, (_Float16)f.z, (_Float16)f.w };
    *(half4*)(out + (size_t)blockIdx.y * 1024 * 1024 + i) = h;
}

// ---------------------------------------------------------------------------
// Fused QKV: grid (64,8,3) = 1536 blocks. z=0 Q[t][d], z=1 K[s][d] (swapped,
// half4 along d); z=2 Vt[b][d][t] (unswapped, half4 along t).
// ---------------------------------------------------------------------------
__global__ __launch_bounds__(256) void qkv_gemm_k(
    const _Float16* __restrict__ xh, const _Float16* __restrict__ Wh,
    _Float16* __restrict__ Q, _Float16* __restrict__ K, _Float16* __restrict__ Vt)
{
    __shared__ __align__(16) _Float16 ldsA[2 * 128 * 32];
    __shared__ __align__(16) _Float16 ldsB[2 * 128 * 32];
    const int tileM = blockIdx.x * 128;
    const int tileN = blockIdx.y * 128;
    const int z     = blockIdx.z;
    const _Float16* W = Wh + (size_t)z * 1024 * 1024;

    const int lane = threadIdx.x & 63;
    const int wm = (threadIdx.x >> 7) & 1, wn = (threadIdx.x >> 6) & 1;
    const int lr = lane & 15, lq = lane >> 4;

    if (z == 2) {
        f32x4 acc[4][4] = {};
        gemm_nt_dbuf<128, 128, false>(xh + (size_t)tileM * 1024,
                                      W + (size_t)tileN * 1024,
                                      1024, 1024, 0, 1024, ldsA, ldsB, acc);
#pragma unroll
        for (int mi = 0; mi < 4; ++mi)
#pragma unroll
            for (int ni = 0; ni < 4; ++ni) {
                int m0 = tileM + wm * 64 + mi * 16 + lq * 4;
                int n  = tileN + wn * 64 + ni * 16 + lr;
                int b = m0 >> 11, tt = m0 & 2047;
                half4 h = { (_Float16)acc[mi][ni][0], (_Float16)acc[mi][ni][1],
                            (_Float16)acc[mi][ni][2], (_Float16)acc[mi][ni][3] };
                *(half4*)(Vt + (size_t)b * 2048 * 1024 + (size_t)n * 2048 + tt) = h;
            }
    } else {
        f32x4 acc[4][4] = {};
        gemm_nt_dbuf<128, 128, true>(xh + (size_t)tileM * 1024,
                                     W + (size_t)tileN * 1024,
                                     1024, 1024, 0, 1024, ldsA, ldsB, acc);
        _Float16* O = (z == 0) ? Q : K;
#pragma unroll
        for (int mi = 0; mi < 4; ++mi)
#pragma unroll
            for (int ni = 0; ni < 4; ++ni) {
                int tt = tileM + wm * 64 + mi * 16 + lr;
                int d0 = tileN + wn * 64 + ni * 16 + lq * 4;
                half4 h = { (_Float16)acc[mi][ni][0], (_Float16)acc[mi][ni][1],
                            (_Float16)acc[mi][ni][2], (_Float16)acc[mi][ni][3] };
                *(half4*)(O + (size_t)tt * 1024 + d0) = h;
            }
    }
}

// ---------------------------------------------------------------------------
// Scores (fp16): 128x128 tiles, grid (16,16,4), early-return above diagonal.
// Swapped MFMA -> half4 along s, causal mask to 0 in-tile.
// ---------------------------------------------------------------------------
__global__ __launch_bounds__(256) void scores_gemm_k(
    const _Float16* __restrict__ Q, const _Float16* __restrict__ K,
    _Float16* __restrict__ S)
{
    const int ti = blockIdx.x, si = blockIdx.y;
    if (si > ti) return;                     // fully above diagonal
    const int tileT = ti * 128, tileS = si * 128, b = blockIdx.z;

    __shared__ __align__(16) _Float16 ldsA[2 * 128 * 32];
    __shared__ __align__(16) _Float16 ldsB[2 * 128 * 32];
    f32x4 acc[4][4] = {};
    gemm_nt_dbuf<128, 128, true>(
        Q + (size_t)b * 2048 * 1024 + (size_t)tileT * 1024,
        K + (size_t)b * 2048 * 1024 + (size_t)tileS * 1024,
        1024, 1024, 0, 1024, ldsA, ldsB, acc);

    const int lane = threadIdx.x & 63;
    const int wm = (threadIdx.x >> 7) & 1, wn = (threadIdx.x >> 6) & 1;
    const int lr = lane & 15, lq = lane >> 4;
    const float scale = 0.03125f;  // 1024^-0.5

#pragma unroll
    for (int mi = 0; mi < 4; ++mi)
#pragma unroll
        for (int ni = 0; ni < 4; ++ni) {
            int tt = tileT + wm * 64 + mi * 16 + lr;
            int s0 = tileS + wn * 64 + ni * 16 + lq * 4;
            half4 h;
#pragma unroll
            for (int r = 0; r < 4; ++r)
                h[r] = (s0 + r <= tt) ? (_Float16)(acc[mi][ni][r] * scale)
                                      : (_Float16)0.f;
            *(half4*)(S + ((size_t)b * 2048 + tt) * 2048 + s0) = h;
        }
}

// ---------------------------------------------------------------------------
// Softmax: ONE WAVE per row, half8 loads, 64-lane shuffle reduce, no LDS,
// no block barriers. Masked lanes contribute exp->0; stores zero-fill s>t
// (so PV's K range is fully defined regardless of scores' written region).
// ---------------------------------------------------------------------------
__global__ __launch_bounds__(256) void softmax_k(_Float16* __restrict__ S)
{
    const int w    = threadIdx.x >> 6;
    const int lane = threadIdx.x & 63;
    const int t    = blockIdx.x * 4 + w;
    const int b    = blockIdx.y;
    _Float16* row = S + ((size_t)b * 2048 + t) * 2048;

    float x[32];
    float mx = -1e30f;
#pragma unroll
    for (int j = 0; j < 4; ++j) {
        half8 h = *(const half8*)(row + j * 512 + lane * 8);
#pragma unroll
        for (int e = 0; e < 8; ++e) {
            int s = j * 512 + lane * 8 + e;
            float f = (s <= t) ? (float)h[e] : -1e30f;
            x[j * 8 + e] = f;
            mx = fmaxf(mx, f);
        }
    }
#pragma unroll
    for (int o = 32; o > 0; o >>= 1) mx = fmaxf(mx, __shfl_xor(mx, o));

    float sum = 0.f;
#pragma unroll
    for (int i = 0; i < 32; ++i) {
        float e = __expf(x[i] - mx);   // masked: exp(-huge) -> 0
        x[i] = e;
        sum += e;
    }
#pragma unroll
    for (int o = 32; o > 0; o >>= 1) sum += __shfl_xor(sum, o);
    const float inv = 1.0f / sum;

#pragma unroll
    for (int j = 0; j < 4; ++j) {
        half8 p;
#pragma unroll
        for (int e = 0; e < 8; ++e) p[e] = (_Float16)(x[j * 8 + e] * inv);
        *(half8*)(row + j * 512 + lane * 8) = p;
    }
}

// ---------------------------------------------------------------------------
// PV: 128(t) x 64(d) tiles -> grid (16,16,4) = 1024 blocks, kEnd = tileT+128.
// Longest t-tiles first. Swapped MFMA -> float4 along d.
// ---------------------------------------------------------------------------
__global__ __launch_bounds__(256) void pv_gemm_k(
    const _Float16* __restrict__ P, const _Float16* __restrict__ Vt,
    float* __restrict__ out)
{
    __shared__ __align__(16) _Float16 ldsA[2 * 128 * 32];
    __shared__ __align__(16) _Float16 ldsB[2 * 64 * 32];
    const int tileT = (15 - blockIdx.x) * 128;   // longest-first
    const int tileD = blockIdx.y * 64;
    const int b     = blockIdx.z;
    const int kEnd  = tileT + 128;

    f32x4 acc[4][2] = {};
    gemm_nt_dbuf<128, 64, true>(
        P + ((size_t)b * 2048 + tileT) * 2048,
        Vt + (size_t)b * 1024 * 2048 + (size_t)tileD * 2048,
        2048, 2048, 0, kEnd, ldsA, ldsB, acc);

    const int lane = threadIdx.x & 63;
    const int wm = (threadIdx.x >> 7) & 1, wn = (threadIdx.x >> 6) & 1;
    const int lr = lane & 15, lq = lane >> 4;

#pragma unroll
    for (int mi = 0; mi < 4; ++mi)
#pragma unroll
        for (int ni = 0; ni < 2; ++ni) {
            int tt = tileT + wm * 64 + mi * 16 + lr;
            int d0 = tileD + wn * 32 + ni * 16 + lq * 4;
            *(f32x4*)(out + ((size_t)b * 2048 + tt) * 1024 + d0) = acc[mi][ni];
        }
}

// ---------------------------------------------------------------------------
extern "C" void kernel_launch(void* const* d_in, const int* in_sizes, int n_in,
                              void* d_out, int out_size, void* d_ws, size_t ws_size,
                              hipStream_t stream)
{
    const float* x  = (const float*)d_in[0];
    const float* Wq = (const float*)d_in[1];
    const float* Wk = (const float*)d_in[2];
    const float* Wv = (const float*)d_in[3];
    float* out = (float*)d_out;

    char* ws = (char*)d_ws;
    // layout (MB): xh 0..16 | Wh 16..22 | Q 22..38 | K 38..54 | Vt 54..70 |
    // S16 70..102 (P aliases S).  Total 102 MB.
    _Float16* xh = (_Float16*)(ws);
    _Float16* Wh = (_Float16*)(ws + (16u << 20));
    _Float16* Qh = (_Float16*)(ws + (22u << 20));
    _Float16* Kh = (_Float16*)(ws + (38u << 20));
    _Float16* Vt = (_Float16*)(ws + (54u << 20));
    _Float16* S  = (_Float16*)(ws + (70u << 20));

    f32tof16_k<<<8192, 256, 0, stream>>>(x, xh, 4 * 2048 * 1024);
    wconv_k<<<dim3(1024, 3), 256, 0, stream>>>(Wq, Wk, Wv, Wh);

    qkv_gemm_k<<<dim3(64, 8, 3), 256, 0, stream>>>(xh, Wh, Qh, Kh, Vt);

    scores_gemm_k<<<dim3(16, 16, 4), 256, 0, stream>>>(Qh, Kh, S);
    softmax_k<<<dim3(512, 4), 256, 0, stream>>>(S);
    pv_gemm_k<<<dim3(16, 16, 4), 256, 0, stream>>>(S, Vt, out);
}

// Round 5
// 262.840 us; speedup vs baseline: 1.1653x; 1.0837x over previous
//
#include <hip/hip_runtime.h>
#include <hip/hip_fp16.h>

// B=4, T=2048, C=1024. Single-head causal attention, fp32 in/out.
// Internals fp16 (MFMA f32_16x16x32_f16), fp32 accum + fp32 softmax.
// R5: BK=64 K-step (32 MFMA per barrier-pair, single-buffered 2-barrier
// loop — dbuf removed, proven defeated by compiler waitcnt). New 128B-row
// LDS swizzle chunk(R,c)=8R+(c^(R&7)): 2-way max aliasing (free).

typedef __attribute__((ext_vector_type(8))) _Float16 half8;
typedef __attribute__((ext_vector_type(4))) _Float16 half4;
typedef __attribute__((ext_vector_type(4))) float f32x4;

#define AS1 __attribute__((address_space(1)))
#define AS3 __attribute__((address_space(3)))

__device__ __forceinline__ void gload_lds16(const void* g, void* l) {
    // async global->LDS, 16B/lane; LDS dest = wave-uniform base + lane*16
    __builtin_amdgcn_global_load_lds((AS1 void*)g, (AS3 void*)l, 16, 0, 0);
}

// ---------------------------------------------------------------------------
// NT-GEMM core, TM x TN tile, BK=64, 256 thr = 4 waves, each wave
// (TM/2)x(TN/2) of 16x16x32 MFMA fragments. A[m][k] lda, B[n][k] ldb,
// k in [k0,k1), k1-k0 multiple of 64.
// LDS: row R = 8 chunks of 16B; chunk(R,c) = 8R + (c ^ (R & 7)).
//  - staging: thread-chunk f holds global (row=f>>3, colchunk=(f&7)^((f>>3)&7));
//    8 consecutive threads read one permuted 128B row segment (coalesced).
//  - fragment read (row R, k-half h, lq): chunk 8R + ((h*4+lq)^(R&7)).
//    Lanes R..R+7 of an lq-group tile all 32 banks once; R+8 group repeats
//    -> 2-way = free.
// Per iteration: 1 gload phase (TM/32 + TN/32 instrs/thread), 2 compute
// halves of (FM+FN ds_read_b128 + FM*FN MFMA) each.
// SWAP: mfma(b,a) -> C^T fragments (cols consecutive per lane).
// ---------------------------------------------------------------------------
template<int TM, int TN, bool SWAP>
__device__ __forceinline__ void gemm_nt_core(
    const _Float16* __restrict__ A, const _Float16* __restrict__ B,
    int lda, int ldb, int k0, int k1,
    _Float16* ldsA, _Float16* ldsB,      // sized TM*64, TN*64 halves
    f32x4 acc[TM / 32][TN / 32])
{
    constexpr int FM = TM / 32, FN = TN / 32;
    constexpr int NA = TM / 32, NB = TN / 32;   // 16B chunks per thread
    const int t    = threadIdx.x;
    const int lane = t & 63;
    const int wm   = (t >> 7) & 1;
    const int wn   = (t >> 6) & 1;
    const int lr   = lane & 15;
    const int lq   = lane >> 4;

    const _Float16* ga[NA]; int loA[NA];
    const _Float16* gb[NB]; int loB[NB];
#pragma unroll
    for (int i = 0; i < NA; ++i) {
        int f = t + 256 * i;
        int r = f >> 3, c = (f & 7) ^ ((f >> 3) & 7);
        ga[i] = A + (size_t)r * lda + c * 8;
        loA[i] = f * 8;
    }
#pragma unroll
    for (int i = 0; i < NB; ++i) {
        int f = t + 256 * i;
        int r = f >> 3, c = (f & 7) ^ ((f >> 3) & 7);
        gb[i] = B + (size_t)r * ldb + c * 8;
        loB[i] = f * 8;
    }

    // fragment offsets (halves) for the two k-halves
    int offA[2][FM], offB[2][FN];
#pragma unroll
    for (int h = 0; h < 2; ++h) {
#pragma unroll
        for (int i = 0; i < FM; ++i) {
            int R = wm * (TM / 2) + i * 16 + lr;
            offA[h][i] = (8 * R + ((h * 4 + lq) ^ (R & 7))) * 8;
        }
#pragma unroll
        for (int i = 0; i < FN; ++i) {
            int R = wn * (TN / 2) + i * 16 + lr;
            offB[h][i] = (8 * R + ((h * 4 + lq) ^ (R & 7))) * 8;
        }
    }

    for (int k = k0; k < k1; k += 64) {
        __syncthreads();               // prev compute done before overwrite
#pragma unroll
        for (int i = 0; i < NA; ++i) gload_lds16(ga[i] + k, ldsA + loA[i]);
#pragma unroll
        for (int i = 0; i < NB; ++i) gload_lds16(gb[i] + k, ldsB + loB[i]);
        __syncthreads();               // staging visible

#pragma unroll
        for (int h = 0; h < 2; ++h) {
            half8 af[FM], bf[FN];
#pragma unroll
            for (int i = 0; i < FM; ++i) af[i] = *(const half8*)(ldsA + offA[h][i]);
#pragma unroll
            for (int i = 0; i < FN; ++i) bf[i] = *(const half8*)(ldsB + offB[h][i]);
#pragma unroll
            for (int mi = 0; mi < FM; ++mi)
#pragma unroll
                for (int ni = 0; ni < FN; ++ni) {
                    if constexpr (SWAP)
                        acc[mi][ni] = __builtin_amdgcn_mfma_f32_16x16x32_f16(
                            bf[ni], af[mi], acc[mi][ni], 0, 0, 0);
                    else
                        acc[mi][ni] = __builtin_amdgcn_mfma_f32_16x16x32_f16(
                            af[mi], bf[ni], acc[mi][ni], 0, 0, 0);
                }
        }
    }
}

// ---------------------------------------------------------------------------
__global__ __launch_bounds__(256) void f32tof16_k(
    const float* __restrict__ in, _Float16* __restrict__ out, int n)
{
    int i = (blockIdx.x * 256 + threadIdx.x) * 4;
    if (i < n) {
        float4 f = *(const float4*)(in + i);
        half4 h = { (_Float16)f.x, (_Float16)f.y, (_Float16)f.z, (_Float16)f.w };
        *(half4*)(out + i) = h;
    }
}

__global__ __launch_bounds__(256) void wconv_k(
    const float* __restrict__ Wq, const float* __restrict__ Wk,
    const float* __restrict__ Wv, _Float16* __restrict__ out)
{
    const float* src = (blockIdx.y == 0) ? Wq : (blockIdx.y == 1) ? Wk : Wv;
    int i = (blockIdx.x * 256 + threadIdx.x) * 4;
    float4 f = *(const float4*)(src + i);
    half4 h = { (_Float16)f.x, (_Float16)f.y, (_Float16)f.z, (_Float16)f.w };
    *(half4*)(out + (size_t)blockIdx.y * 1024 * 1024 + i) = h;
}

// ---------------------------------------------------------------------------
// Fused QKV: grid (64,8,3) = 1536 blocks. z=0 Q[t][d], z=1 K[s][d] (swapped,
// half4 along d); z=2 Vt[b][d][t] (unswapped, half4 along t).
// ---------------------------------------------------------------------------
__global__ __launch_bounds__(256) void qkv_gemm_k(
    const _Float16* __restrict__ xh, const _Float16* __restrict__ Wh,
    _Float16* __restrict__ Q, _Float16* __restrict__ K, _Float16* __restrict__ Vt)
{
    __shared__ __align__(16) _Float16 ldsA[128 * 64];
    __shared__ __align__(16) _Float16 ldsB[128 * 64];
    const int tileM = blockIdx.x * 128;
    const int tileN = blockIdx.y * 128;
    const int z     = blockIdx.z;
    const _Float16* W = Wh + (size_t)z * 1024 * 1024;

    const int lane = threadIdx.x & 63;
    const int wm = (threadIdx.x >> 7) & 1, wn = (threadIdx.x >> 6) & 1;
    const int lr = lane & 15, lq = lane >> 4;

    if (z == 2) {
        f32x4 acc[4][4] = {};
        gemm_nt_core<128, 128, false>(xh + (size_t)tileM * 1024,
                                      W + (size_t)tileN * 1024,
                                      1024, 1024, 0, 1024, ldsA, ldsB, acc);
#pragma unroll
        for (int mi = 0; mi < 4; ++mi)
#pragma unroll
            for (int ni = 0; ni < 4; ++ni) {
                int m0 = tileM + wm * 64 + mi * 16 + lq * 4;
                int n  = tileN + wn * 64 + ni * 16 + lr;
                int b = m0 >> 11, tt = m0 & 2047;
                half4 h = { (_Float16)acc[mi][ni][0], (_Float16)acc[mi][ni][1],
                            (_Float16)acc[mi][ni][2], (_Float16)acc[mi][ni][3] };
                *(half4*)(Vt + (size_t)b * 2048 * 1024 + (size_t)n * 2048 + tt) = h;
            }
    } else {
        f32x4 acc[4][4] = {};
        gemm_nt_core<128, 128, true>(xh + (size_t)tileM * 1024,
                                     W + (size_t)tileN * 1024,
                                     1024, 1024, 0, 1024, ldsA, ldsB, acc);
        _Float16* O = (z == 0) ? Q : K;
#pragma unroll
        for (int mi = 0; mi < 4; ++mi)
#pragma unroll
            for (int ni = 0; ni < 4; ++ni) {
                int tt = tileM + wm * 64 + mi * 16 + lr;
                int d0 = tileN + wn * 64 + ni * 16 + lq * 4;
                half4 h = { (_Float16)acc[mi][ni][0], (_Float16)acc[mi][ni][1],
                            (_Float16)acc[mi][ni][2], (_Float16)acc[mi][ni][3] };
                *(half4*)(O + (size_t)tt * 1024 + d0) = h;
            }
    }
}

// ---------------------------------------------------------------------------
// Scores (fp16): 128x128 tiles, grid (16,16,4), early-return above diagonal.
// Swapped MFMA -> half4 along s, causal mask to 0 in-tile.
// ---------------------------------------------------------------------------
__global__ __launch_bounds__(256) void scores_gemm_k(
    const _Float16* __restrict__ Q, const _Float16* __restrict__ K,
    _Float16* __restrict__ S)
{
    const int ti = blockIdx.x, si = blockIdx.y;
    if (si > ti) return;                     // fully above diagonal
    const int tileT = ti * 128, tileS = si * 128, b = blockIdx.z;

    __shared__ __align__(16) _Float16 ldsA[128 * 64];
    __shared__ __align__(16) _Float16 ldsB[128 * 64];
    f32x4 acc[4][4] = {};
    gemm_nt_core<128, 128, true>(
        Q + (size_t)b * 2048 * 1024 + (size_t)tileT * 1024,
        K + (size_t)b * 2048 * 1024 + (size_t)tileS * 1024,
        1024, 1024, 0, 1024, ldsA, ldsB, acc);

    const int lane = threadIdx.x & 63;
    const int wm = (threadIdx.x >> 7) & 1, wn = (threadIdx.x >> 6) & 1;
    const int lr = lane & 15, lq = lane >> 4;
    const float scale = 0.03125f;  // 1024^-0.5

#pragma unroll
    for (int mi = 0; mi < 4; ++mi)
#pragma unroll
        for (int ni = 0; ni < 4; ++ni) {
            int tt = tileT + wm * 64 + mi * 16 + lr;
            int s0 = tileS + wn * 64 + ni * 16 + lq * 4;
            half4 h;
#pragma unroll
            for (int r = 0; r < 4; ++r)
                h[r] = (s0 + r <= tt) ? (_Float16)(acc[mi][ni][r] * scale)
                                      : (_Float16)0.f;
            *(half4*)(S + ((size_t)b * 2048 + tt) * 2048 + s0) = h;
        }
}

// ---------------------------------------------------------------------------
// Softmax: ONE WAVE per row, half8 loads, 64-lane shuffle reduce, no LDS,
// no block barriers. Zero-fills s>t (PV's K range fully defined).
// ---------------------------------------------------------------------------
__global__ __launch_bounds__(256) void softmax_k(_Float16* __restrict__ S)
{
    const int w    = threadIdx.x >> 6;
    const int lane = threadIdx.x & 63;
    const int t    = blockIdx.x * 4 + w;
    const int b    = blockIdx.y;
    _Float16* row = S + ((size_t)b * 2048 + t) * 2048;

    float x[32];
    float mx = -1e30f;
#pragma unroll
    for (int j = 0; j < 4; ++j) {
        half8 h = *(const half8*)(row + j * 512 + lane * 8);
#pragma unroll
        for (int e = 0; e < 8; ++e) {
            int s = j * 512 + lane * 8 + e;
            float f = (s <= t) ? (float)h[e] : -1e30f;
            x[j * 8 + e] = f;
            mx = fmaxf(mx, f);
        }
    }
#pragma unroll
    for (int o = 32; o > 0; o >>= 1) mx = fmaxf(mx, __shfl_xor(mx, o));

    float sum = 0.f;
#pragma unroll
    for (int i = 0; i < 32; ++i) {
        float e = __expf(x[i] - mx);   // masked: exp(-huge) -> 0
        x[i] = e;
        sum += e;
    }
#pragma unroll
    for (int o = 32; o > 0; o >>= 1) sum += __shfl_xor(sum, o);
    const float inv = 1.0f / sum;

#pragma unroll
    for (int j = 0; j < 4; ++j) {
        half8 p;
#pragma unroll
        for (int e = 0; e < 8; ++e) p[e] = (_Float16)(x[j * 8 + e] * inv);
        *(half8*)(row + j * 512 + lane * 8) = p;
    }
}

// ---------------------------------------------------------------------------
// PV: 128(t) x 64(d) tiles -> grid (16,16,4) = 1024 blocks, kEnd = tileT+128
// (multiple of 64 ✓). Longest t-tiles first. Swapped MFMA -> float4 along d.
// ---------------------------------------------------------------------------
__global__ __launch_bounds__(256) void pv_gemm_k(
    const _Float16* __restrict__ P, const _Float16* __restrict__ Vt,
    float* __restrict__ out)
{
    __shared__ __align__(16) _Float16 ldsA[128 * 64];
    __shared__ __align__(16) _Float16 ldsB[64 * 64];
    const int tileT = (15 - blockIdx.x) * 128;   // longest-first
    const int tileD = blockIdx.y * 64;
    const int b     = blockIdx.z;
    const int kEnd  = tileT + 128;

    f32x4 acc[4][2] = {};
    gemm_nt_core<128, 64, true>(
        P + ((size_t)b * 2048 + tileT) * 2048,
        Vt + (size_t)b * 1024 * 2048 + (size_t)tileD * 2048,
        2048, 2048, 0, kEnd, ldsA, ldsB, acc);

    const int lane = threadIdx.x & 63;
    const int wm = (threadIdx.x >> 7) & 1, wn = (threadIdx.x >> 6) & 1;
    const int lr = lane & 15, lq = lane >> 4;

#pragma unroll
    for (int mi = 0; mi < 4; ++mi)
#pragma unroll
        for (int ni = 0; ni < 2; ++ni) {
            int tt = tileT + wm * 64 + mi * 16 + lr;
            int d0 = tileD + wn * 32 + ni * 16 + lq * 4;
            *(f32x4*)(out + ((size_t)b * 2048 + tt) * 1024 + d0) = acc[mi][ni];
        }
}

// ---------------------------------------------------------------------------
extern "C" void kernel_launch(void* const* d_in, const int* in_sizes, int n_in,
                              void* d_out, int out_size, void* d_ws, size_t ws_size,
                              hipStream_t stream)
{
    const float* x  = (const float*)d_in[0];
    const float* Wq = (const float*)d_in[1];
    const float* Wk = (const float*)d_in[2];
    const float* Wv = (const float*)d_in[3];
    float* out = (float*)d_out;

    char* ws = (char*)d_ws;
    // layout (MB): xh 0..16 | Wh 16..22 | Q 22..38 | K 38..54 | Vt 54..70 |
    // S16 70..102 (P aliases S).  Total 102 MB.
    _Float16* xh = (_Float16*)(ws);
    _Float16* Wh = (_Float16*)(ws + (16u << 20));
    _Float16* Qh = (_Float16*)(ws + (22u << 20));
    _Float16* Kh = (_Float16*)(ws + (38u << 20));
    _Float16* Vt = (_Float16*)(ws + (54u << 20));
    _Float16* S  = (_Float16*)(ws + (70u << 20));

    f32tof16_k<<<8192, 256, 0, stream>>>(x, xh, 4 * 2048 * 1024);
    wconv_k<<<dim3(1024, 3), 256, 0, stream>>>(Wq, Wk, Wv, Wh);

    qkv_gemm_k<<<dim3(64, 8, 3), 256, 0, stream>>>(xh, Wh, Qh, Kh, Vt);

    scores_gemm_k<<<dim3(16, 16, 4), 256, 0, stream>>>(Qh, Kh, S);
    softmax_k<<<dim3(512, 4), 256, 0, stream>>>(S);
    pv_gemm_k<<<dim3(16, 16, 4), 256, 0, stream>>>(S, Vt, out);
}